// Round 2
// baseline (431.720 us; speedup 1.0000x reference)
//
#include <hip/hip_runtime.h>

typedef __bf16 bf16;
typedef __bf16 bf16x4 __attribute__((ext_vector_type(4)));
typedef __bf16 bf16x8 __attribute__((ext_vector_type(8)));
typedef float f32x4 __attribute__((ext_vector_type(4)));

#define B_ 2
#define S_ 2048
#define D_ 2048
#define H_ 16
#define DH_ 128
#define QKVN 6144

__device__ __forceinline__ void async_load16(const bf16* g, bf16* l) {
    __builtin_amdgcn_global_load_lds((const __attribute__((address_space(1))) void*)g,
                                     (__attribute__((address_space(3))) void*)l, 16, 0, 0);
}

__device__ __forceinline__ unsigned int bf16_bits(float x) {
    bf16 h = (bf16)x;
    return (unsigned int)__builtin_bit_cast(unsigned short, h);
}

// ---------------- x cast: f32 -> bf16, 8 elems/thread -----------------------------
__global__ __launch_bounds__(256) void cvt_kernel(const float* __restrict__ src,
                                                  bf16* __restrict__ dst) {
    size_t i = (size_t)blockIdx.x * 256 + threadIdx.x;
    const float4* s = (const float4*)src;
    float4 a = s[2 * i], b = s[2 * i + 1];
    bf16x8 o;
    o[0] = (bf16)a.x; o[1] = (bf16)a.y; o[2] = (bf16)a.z; o[3] = (bf16)a.w;
    o[4] = (bf16)b.x; o[5] = (bf16)b.y; o[6] = (bf16)b.z; o[7] = (bf16)b.w;
    *(bf16x8*)(dst + 8 * i) = o;
}

// ------- weight transpose + cast: W[K][N] f32 -> Wt[N][K] bf16, 4 matrices --------
__global__ __launch_bounds__(256) void wtrans_kernel(const float* __restrict__ Wq,
                                                     const float* __restrict__ Wk,
                                                     const float* __restrict__ Wv,
                                                     const float* __restrict__ Wo,
                                                     bf16* __restrict__ WqkvT,
                                                     bf16* __restrict__ WoT) {
    __shared__ unsigned int tile[64][65];  // bf16 bits in low half
    int z = blockIdx.z;
    const float* src = (z == 0) ? Wq : (z == 1) ? Wk : (z == 2) ? Wv : Wo;
    bf16* dst = (z < 3) ? (WqkvT + (size_t)z * D_ * D_) : WoT;
    int r0 = blockIdx.y * 64, c0 = blockIdx.x * 64;
    int t = threadIdx.x;
    int tr = t >> 4, tc4 = (t & 15) * 4;
#pragma unroll
    for (int it = 0; it < 4; ++it) {
        int r = it * 16 + tr;
        float4 v = *(const float4*)(src + (size_t)(r0 + r) * D_ + c0 + tc4);
        tile[r][tc4 + 0] = bf16_bits(v.x);
        tile[r][tc4 + 1] = bf16_bits(v.y);
        tile[r][tc4 + 2] = bf16_bits(v.z);
        tile[r][tc4 + 3] = bf16_bits(v.w);
    }
    __syncthreads();
#pragma unroll
    for (int it = 0; it < 4; ++it) {
        int a = it * 16 + tr;
        unsigned u0 = tile[tc4 + 0][a], u1 = tile[tc4 + 1][a];
        unsigned u2 = tile[tc4 + 2][a], u3 = tile[tc4 + 3][a];
        uint2 v;
        v.x = (u0 & 0xffffu) | (u1 << 16);
        v.y = (u2 & 0xffffu) | (u3 << 16);
        *(uint2*)(dst + (size_t)(c0 + a) * D_ + r0 + tc4) = v;
    }
}

// ---------------- V transpose: qkv[:,4096+h*128+dh] -> vt[bh][dh][s], bf16 --------
__global__ __launch_bounds__(256) void vtrans_kernel(const bf16* __restrict__ qkv,
                                                     bf16* __restrict__ vt) {
    __shared__ unsigned int tile[64][65];
    int bh = blockIdx.z;
    int b = bh >> 4, h = bh & 15;
    int s0 = blockIdx.x * 64, d0 = blockIdx.y * 64;
    int t = threadIdx.x, tr = t >> 4, tc4 = (t & 15) * 4;
#pragma unroll
    for (int it = 0; it < 4; ++it) {
        int r = it * 16 + tr;  // s offset
        uint2 v = *(const uint2*)(qkv + (size_t)(b * S_ + s0 + r) * QKVN + 2 * D_ + h * DH_ + d0 + tc4);
        tile[r][tc4 + 0] = v.x & 0xffffu;
        tile[r][tc4 + 1] = v.x >> 16;
        tile[r][tc4 + 2] = v.y & 0xffffu;
        tile[r][tc4 + 3] = v.y >> 16;
    }
    __syncthreads();
#pragma unroll
    for (int it = 0; it < 4; ++it) {
        int a = it * 16 + tr;  // dh offset
        unsigned u0 = tile[tc4 + 0][a], u1 = tile[tc4 + 1][a];
        unsigned u2 = tile[tc4 + 2][a], u3 = tile[tc4 + 3][a];
        uint2 v;
        v.x = (u0 & 0xffffu) | (u1 << 16);
        v.y = (u2 & 0xffffu) | (u3 << 16);
        *(uint2*)(vt + (size_t)bh * DH_ * S_ + (size_t)(d0 + a) * S_ + s0 + tc4) = v;
    }
}

// ---------------- m97-style GEMM: C[M][N] = A[M][K] @ Bt[N][K]^T ------------------
template <typename CT>
__global__ __launch_bounds__(256) void gemm_bt(const bf16* __restrict__ A,
                                               const bf16* __restrict__ Bt,
                                               CT* __restrict__ C,
                                               int M, int N, int K) {
    __shared__ __align__(16) bf16 As[128 * 32];
    __shared__ __align__(16) bf16 Bs[128 * 32];
    int t = threadIdx.x;
    int w = t >> 6, l = t & 63;
    int quad = l >> 4, lr = l & 15;
    int wr = w >> 1, wc = w & 1;
    size_t m0 = (size_t)blockIdx.y * 128, n0 = (size_t)blockIdx.x * 128;
    int srow = l >> 2, scol = (l & 3) * 8;

    f32x4 acc[4][4];
#pragma unroll
    for (int i = 0; i < 4; ++i)
#pragma unroll
        for (int j = 0; j < 4; ++j) acc[i][j] = (f32x4){0.f, 0.f, 0.f, 0.f};

    for (int k0 = 0; k0 < K; k0 += 32) {
        __syncthreads();
#pragma unroll
        for (int i = 0; i < 2; ++i) {
            int c = w * 2 + i;
            async_load16(A + (m0 + c * 16 + srow) * (size_t)K + k0 + scol, As + c * 512);
            async_load16(Bt + (n0 + c * 16 + srow) * (size_t)K + k0 + scol, Bs + c * 512);
        }
        asm volatile("s_waitcnt vmcnt(0)" ::: "memory");
        __syncthreads();
        bf16x8 af[4], bfr[4];
#pragma unroll
        for (int i = 0; i < 4; ++i) af[i] = *(const bf16x8*)(As + (wr * 64 + i * 16 + lr) * 32 + quad * 8);
#pragma unroll
        for (int j = 0; j < 4; ++j) bfr[j] = *(const bf16x8*)(Bs + (wc * 64 + j * 16 + lr) * 32 + quad * 8);
#pragma unroll
        for (int i = 0; i < 4; ++i)
#pragma unroll
            for (int j = 0; j < 4; ++j)
                acc[i][j] = __builtin_amdgcn_mfma_f32_16x16x32_bf16(af[i], bfr[j], acc[i][j], 0, 0, 0);
    }

    size_t bm = m0 + wr * 64 + quad * 4;
    size_t bn = n0 + wc * 64 + lr;
#pragma unroll
    for (int i = 0; i < 4; ++i)
#pragma unroll
        for (int j = 0; j < 4; ++j)
#pragma unroll
            for (int r = 0; r < 4; ++r)
                C[(bm + i * 16 + r) * (size_t)N + bn + j * 16] = (CT)acc[i][j][r];
}

// ========== 256x256 8-phase GEMM for QKV: C[4096][6144] = A[4096][2048] @ Bt^T ====
// T2 st_16x32 swizzle (byte ^= ((byte>>9)&1)<<5), applied as inverse-swizzled
// global SOURCE (global_load_lds dest must stay linear) + swizzled ds_read.
// T3/T4: 4 phases per K-tile (quadrants (mh,nh)), half-tile staging in
// consumption order A0,B0,B1,A1; counted vmcnt placed BEFORE a barrier so the
// completion guarantee is collective (per-wave vmcnt -> s_barrier -> all
// waves' older loads LDS-visible). Steady state vmcnt(4) at ends of phases
// 0,1,3 (none at 2). T5: setprio around each 16-MFMA cluster.
#define QK_K 2048
#define QK_N 6144

__device__ __forceinline__ bf16x8 lds_frag(const bf16* tile, int row, int colByte) {
    int off = row * 128 + (colByte ^ (((row >> 2) & 1) << 5));
    return *(const bf16x8*)((const char*)tile + off);
}

template <int MH, int NH>
__device__ __forceinline__ void mmaq8(f32x4 (&acc)[8][4], const bf16x8 (&afr)[4][2],
                                      const bf16x8 (&bf)[2][2]) {
    __builtin_amdgcn_s_setprio(1);
#pragma unroll
    for (int i = 0; i < 4; ++i)
#pragma unroll
        for (int j = 0; j < 2; ++j)
#pragma unroll
            for (int kk = 0; kk < 2; ++kk)
                acc[MH * 4 + i][NH * 2 + j] = __builtin_amdgcn_mfma_f32_16x16x32_bf16(
                    afr[i][kk], bf[j][kk], acc[MH * 4 + i][NH * 2 + j], 0, 0, 0);
    __builtin_amdgcn_s_setprio(0);
}

__global__ __launch_bounds__(512, 2) void gemm_qkv(const bf16* __restrict__ A,
                                                   const bf16* __restrict__ Bt,
                                                   bf16* __restrict__ C) {
    __shared__ __align__(16) bf16 As[2][256 * 64];
    __shared__ __align__(16) bf16 Bs[2][256 * 64];

    int t = threadIdx.x;
    int wid = t >> 6, lane = t & 63;
    int quad = lane >> 4, lr = lane & 15;
    int wr = wid >> 2, wn = wid & 3;  // 2 x 4 wave grid

    // XCD swizzle: 384 wgs, 8 XCDs x 48. Column-major: each XCD owns 3 disjoint
    // B-panels (read exactly once chip-wide); A panels stream (L3-resident).
    int bid = blockIdx.x;
    int swz = (bid & 7) * 48 + (bid >> 3);
    int tn = swz >> 4, tm = swz & 15;
    size_t m0 = (size_t)tm * 256, n0 = (size_t)tn * 256;

    // staging geometry: chunk idx = r*512 + t; row = idx>>3, col-chunk = idx&7;
    // inverse-swizzle source col-chunk: flip bit1 when row bit2 set.
    int row_r[2], c8s_r[2];
#pragma unroll
    for (int r = 0; r < 2; ++r) {
        int idx = r * 512 + t;
        row_r[r] = idx >> 3;
        c8s_r[r] = (idx & 7) ^ (((row_r[r] >> 2) & 1) << 1);
    }

    auto stA = [&](int kt, int bufi, int h) {
#pragma unroll
        for (int r = 0; r < 2; ++r)
            async_load16(A + (m0 + h * 128 + row_r[r]) * (size_t)QK_K + kt * 64 + c8s_r[r] * 8,
                         &As[bufi][(h * 1024 + r * 512 + wid * 64) * 8]);
    };
    auto stB = [&](int kt, int bufi, int h) {
#pragma unroll
        for (int r = 0; r < 2; ++r)
            async_load16(Bt + (n0 + h * 128 + row_r[r]) * (size_t)QK_K + kt * 64 + c8s_r[r] * 8,
                         &Bs[bufi][(h * 1024 + r * 512 + wid * 64) * 8]);
    };

    f32x4 acc[8][4];
#pragma unroll
    for (int i = 0; i < 8; ++i)
#pragma unroll
        for (int j = 0; j < 4; ++j) acc[i][j] = (f32x4){0.f, 0.f, 0.f, 0.f};

    bf16x8 afr[4][2], bf0[2][2], bf1[2][2];

    auto readA = [&](int bufi, int mh) {
#pragma unroll
        for (int i = 0; i < 4; ++i)
#pragma unroll
            for (int kk = 0; kk < 2; ++kk)
                afr[i][kk] = lds_frag(As[bufi], mh * 128 + wr * 64 + i * 16 + lr, kk * 64 + quad * 16);
    };
    auto readB = [&](int bufi, int nh, bf16x8 (&bf)[2][2]) {
#pragma unroll
        for (int j = 0; j < 2; ++j)
#pragma unroll
            for (int kk = 0; kk < 2; ++kk)
                bf[j][kk] = lds_frag(Bs[bufi], nh * 128 + wn * 32 + j * 16 + lr, kk * 64 + quad * 16);
    };

    // prologue: stage tile 0 in consumption-guard order A0,B0,B1,A1 (8 loads)
    stA(0, 0, 0);
    stB(0, 0, 0);
    stB(0, 0, 1);
    stA(0, 0, 1);
    asm volatile("s_waitcnt vmcnt(4)" ::: "memory");  // A0,B0 done
    __builtin_amdgcn_s_barrier();

    const int NKT = QK_K / 64;  // 32
    for (int kt = 0; kt < NKT - 1; ++kt) {
        int cb = kt & 1, nb = cb ^ 1;
        // ---- phase 0: quadrant (0,0); stage A0' ----
        readA(cb, 0);
        readB(cb, 0, bf0);
        stA(kt + 1, nb, 0);
        asm volatile("s_waitcnt vmcnt(4)" ::: "memory");  // guard ph1's B1
        __builtin_amdgcn_s_barrier();
        asm volatile("s_waitcnt lgkmcnt(0)" ::: "memory");
        __builtin_amdgcn_sched_barrier(0);
        mmaq8<0, 0>(acc, afr, bf0);
        __builtin_amdgcn_s_barrier();
        // ---- phase 1: quadrant (0,1); stage B0' ----
        readB(cb, 1, bf1);
        stB(kt + 1, nb, 0);
        asm volatile("s_waitcnt vmcnt(4)" ::: "memory");  // guard ph2's A1
        __builtin_amdgcn_s_barrier();
        asm volatile("s_waitcnt lgkmcnt(0)" ::: "memory");
        __builtin_amdgcn_sched_barrier(0);
        mmaq8<0, 1>(acc, afr, bf1);
        __builtin_amdgcn_s_barrier();
        // ---- phase 2: quadrant (1,0); stage B1' ----
        readA(cb, 1);
        stB(kt + 1, nb, 1);
        __builtin_amdgcn_s_barrier();  // ph3 reads nothing: no vmcnt here
        asm volatile("s_waitcnt lgkmcnt(0)" ::: "memory");
        __builtin_amdgcn_sched_barrier(0);
        mmaq8<1, 0>(acc, afr, bf0);
        __builtin_amdgcn_s_barrier();
        // ---- phase 3: quadrant (1,1); stage A1' ----
        stA(kt + 1, nb, 1);
        asm volatile("s_waitcnt vmcnt(4)" ::: "memory");  // guard next ph0's A0',B0'
        __builtin_amdgcn_s_barrier();
        mmaq8<1, 1>(acc, afr, bf1);
        __builtin_amdgcn_s_barrier();
    }

    {  // peeled last tile (no staging)
        int cb = (NKT - 1) & 1;
        readA(cb, 0);
        readB(cb, 0, bf0);
        asm volatile("s_waitcnt vmcnt(2)" ::: "memory");  // guard B1
        __builtin_amdgcn_s_barrier();
        asm volatile("s_waitcnt lgkmcnt(0)" ::: "memory");
        __builtin_amdgcn_sched_barrier(0);
        mmaq8<0, 0>(acc, afr, bf0);
        __builtin_amdgcn_s_barrier();
        readB(cb, 1, bf1);
        asm volatile("s_waitcnt vmcnt(0)" ::: "memory");  // guard A1
        __builtin_amdgcn_s_barrier();
        asm volatile("s_waitcnt lgkmcnt(0)" ::: "memory");
        __builtin_amdgcn_sched_barrier(0);
        mmaq8<0, 1>(acc, afr, bf1);
        __builtin_amdgcn_s_barrier();
        readA(cb, 1);
        __builtin_amdgcn_s_barrier();
        asm volatile("s_waitcnt lgkmcnt(0)" ::: "memory");
        __builtin_amdgcn_sched_barrier(0);
        mmaq8<1, 0>(acc, afr, bf0);
        __builtin_amdgcn_s_barrier();
        mmaq8<1, 1>(acc, afr, bf1);
    }

    // epilogue: C/D layout col=lr, row=quad*4+r per 16x16 frag
#pragma unroll
    for (int mh = 0; mh < 2; ++mh)
#pragma unroll
        for (int i = 0; i < 4; ++i)
#pragma unroll
            for (int nh = 0; nh < 2; ++nh)
#pragma unroll
                for (int j = 0; j < 2; ++j)
#pragma unroll
                    for (int r = 0; r < 4; ++r) {
                        size_t row = m0 + mh * 128 + wr * 64 + i * 16 + quad * 4 + r;
                        size_t col = n0 + nh * 128 + wn * 32 + j * 16 + lr;
                        C[row * QK_N + col] = (bf16)acc[mh * 4 + i][nh * 2 + j][r];
                    }
}

// ---------------- flash attention, causal ----------------------------------------
__global__ __launch_bounds__(128) void attn_kernel(const bf16* __restrict__ qkv,
                                                   const bf16* __restrict__ vt,
                                                   bf16* __restrict__ ctx) {
    __shared__ __align__(16) bf16 Ks[2][64 * 128];    // [key][16B-chunk c ^ (key&7)]
    __shared__ __align__(16) bf16 Vts[2][128 * 64];   // [dh][16B-chunk c ^ (dh&7)]
    __shared__ __align__(16) bf16 Ps[2][32][68];      // per-wave P round-trip

    int y = blockIdx.y;
    int p = blockIdx.x;
    int b = y >> 4, h = y & 15;
    int t = threadIdx.x, w = t >> 6, l = t & 63;
    int quad = l >> 4, lr = l & 15;

    const bf16* qbase = qkv + (size_t)b * S_ * QKVN + h * DH_;
    const bf16* kbase = qbase + D_;
    const bf16* vbase = vt + (size_t)y * DH_ * S_;

    const int qtA = p, qtB = 31 - p;
    const int nA = p + 1;  // iters for tile A; total 33

    auto stage = [&](int kt, int bi) {
#pragma unroll
        for (int ii = 0; ii < 8; ++ii) {
            int i = 8 * w + ii;
            int row = 4 * i + (l >> 4);
            int cl = (l & 15) ^ (row & 7);
            async_load16(kbase + (size_t)(kt * 64 + row) * QKVN + cl * 8, Ks[bi] + i * 512);
        }
#pragma unroll
        for (int ii = 0; ii < 8; ++ii) {
            int i = 8 * w + ii;
            int dh = 8 * i + (l >> 3);
            int cl = (l & 7) ^ (dh & 7);
            async_load16(vbase + (size_t)dh * S_ + kt * 64 + cl * 8, Vts[bi] + i * 512);
        }
    };

    const float sc2 = 0.12751745f;  // (1/sqrt(128)) * log2(e), folded into Q

    int qt = qtA, q0 = qt * 64;
    bf16x8 qf[2][4];
    auto loadQ = [&]() {
#pragma unroll
        for (int g = 0; g < 2; ++g)
#pragma unroll
            for (int kk = 0; kk < 4; ++kk) {
                bf16x8 raw = *(const bf16x8*)(qbase + (size_t)(q0 + w * 32 + g * 16 + lr) * QKVN + kk * 32 + quad * 8);
#pragma unroll
                for (int e = 0; e < 8; ++e) qf[g][kk][e] = (bf16)((float)raw[e] * sc2);
            }
    };
    loadQ();

    float L_r[2][4];
    f32x4 o[2][8];
#pragma unroll
    for (int g = 0; g < 2; ++g) {
#pragma unroll
        for (int r = 0; r < 4; ++r) L_r[g][r] = 0.f;
#pragma unroll
        for (int nt = 0; nt < 8; ++nt) o[g][nt] = (f32x4){0.f, 0.f, 0.f, 0.f};
    }

    auto epilogue = [&](int q0e) {
#pragma unroll
        for (int g = 0; g < 2; ++g) {
#pragma unroll
            for (int d = 1; d < 16; d <<= 1)
#pragma unroll
                for (int r = 0; r < 4; ++r) L_r[g][r] += __shfl_xor(L_r[g][r], d, 64);
#pragma unroll
            for (int r = 0; r < 4; ++r) {
                float inv = __builtin_amdgcn_rcpf(L_r[g][r]);
                int q = q0e + w * 32 + g * 16 + quad * 4 + r;
#pragma unroll
                for (int nt = 0; nt < 8; ++nt)
                    ctx[(size_t)(b * S_ + q) * D_ + h * DH_ + nt * 16 + lr] = (bf16)(o[g][nt][r] * inv);
            }
        }
    };

    stage(0, 0);  // prologue

    for (int it = 0; it < 33; ++it) {
        int buf = it & 1;
        asm volatile("s_waitcnt vmcnt(0)" ::: "memory");
        __syncthreads();
        if (it + 1 < 33) {
            int nit = it + 1;
            int nkt = (nit < nA) ? nit : (nit - nA);
            stage(nkt, buf ^ 1);  // in flight across this iter's compute
        }
        int kt = (it < nA) ? it : (it - nA);

        // S = Q K^T: 2 row-groups x 64 keys; each kf feeds 2 MFMAs
        f32x4 s[2][4];
#pragma unroll
        for (int g = 0; g < 2; ++g)
#pragma unroll
            for (int jt = 0; jt < 4; ++jt) s[g][jt] = (f32x4){0.f, 0.f, 0.f, 0.f};
#pragma unroll
        for (int kk = 0; kk < 4; ++kk)
#pragma unroll
            for (int jt = 0; jt < 4; ++jt) {
                bf16x8 kf = *(const bf16x8*)(Ks[buf] + (jt * 16 + lr) * 128 + ((4 * kk + quad) ^ (lr & 7)) * 8);
                s[0][jt] = __builtin_amdgcn_mfma_f32_16x16x32_bf16(qf[0][kk], kf, s[0][jt], 0, 0, 0);
                s[1][jt] = __builtin_amdgcn_mfma_f32_16x16x32_bf16(qf[1][kk], kf, s[1][jt], 0, 0, 0);
            }

        // exp2 (m=0) + mask (diag k-tile only) + per-lane L accumulation + P store
        bool diag = (kt == qt);
#pragma unroll
        for (int g = 0; g < 2; ++g) {
#pragma unroll
            for (int jt = 0; jt < 4; ++jt) {
                int keyi = jt * 16 + lr;
#pragma unroll
                for (int r = 0; r < 4; ++r) {
                    float s2 = s[g][jt][r];
                    if (diag && keyi > w * 32 + g * 16 + quad * 4 + r) s2 = -3.0e38f;
                    float pv = __builtin_amdgcn_exp2f(s2);
                    s[g][jt][r] = pv;
                    L_r[g][r] += pv;
                }
            }
#pragma unroll
            for (int jt = 0; jt < 4; ++jt)
#pragma unroll
                for (int r = 0; r < 4; ++r)
                    Ps[w][g * 16 + quad * 4 + r][jt * 16 + lr] = (bf16)s[g][jt][r];
        }
        asm volatile("s_waitcnt lgkmcnt(0)" ::: "memory");  // per-wave Ps region

        // O += P @ V: each vf feeds 2 MFMAs
#pragma unroll
        for (int ks = 0; ks < 2; ++ks) {
            bf16x8 pf[2];
#pragma unroll
            for (int g = 0; g < 2; ++g) {
                const bf16* pp = &Ps[w][g * 16 + lr][ks * 32 + quad * 8];
                bf16x4 lo = *(const bf16x4*)pp;
                bf16x4 hi = *(const bf16x4*)(pp + 4);
                pf[g] = __builtin_shufflevector(lo, hi, 0, 1, 2, 3, 4, 5, 6, 7);
            }
#pragma unroll
            for (int nt = 0; nt < 8; ++nt) {
                bf16x8 vf = *(const bf16x8*)(Vts[buf] + (nt * 16 + lr) * 64 + ((4 * ks + quad) ^ (lr & 7)) * 8);
                o[0][nt] = __builtin_amdgcn_mfma_f32_16x16x32_bf16(pf[0], vf, o[0][nt], 0, 0, 0);
                o[1][nt] = __builtin_amdgcn_mfma_f32_16x16x32_bf16(pf[1], vf, o[1][nt], 0, 0, 0);
            }
        }

        // tile switch A -> B after A's diagonal iteration
        if (it == nA - 1) {
            epilogue(q0);
            qt = qtB;
            q0 = qt * 64;
            loadQ();
#pragma unroll
            for (int g = 0; g < 2; ++g) {
#pragma unroll
                for (int r = 0; r < 4; ++r) L_r[g][r] = 0.f;
#pragma unroll
                for (int nt = 0; nt < 8; ++nt) o[g][nt] = (f32x4){0.f, 0.f, 0.f, 0.f};
            }
        }
    }

    epilogue(q0);  // tile B
}

extern "C" void kernel_launch(void* const* d_in, const int* in_sizes, int n_in,
                              void* d_out, int out_size, void* d_ws, size_t ws_size,
                              hipStream_t stream) {
    const float* x  = (const float*)d_in[0];
    const float* Wq = (const float*)d_in[1];
    const float* Wk = (const float*)d_in[2];
    const float* Wv = (const float*)d_in[3];
    const float* Wo = (const float*)d_in[4];
    float* out = (float*)d_out;

    char* ws = (char*)d_ws;
    bf16* WqkvT = (bf16*)(ws);                       // 3*2048*2048*2 = 25165824
    bf16* WoT   = (bf16*)(ws + 25165824);            // 2048*2048*2   =  8388608
    bf16* qkv   = (bf16*)(ws + 33554432);            // 4096*6144*2   = 50331648
    bf16* vt    = (bf16*)(ws + 83886080);            // 32*128*2048*2 = 16777216
    bf16* ctx   = (bf16*)(ws + 100663296);           // 4096*2048*2   = 16777216
    bf16* xb    = (bf16*)(ws + 117440512);           // 4096*2048*2   = 16777216
    // total ws use: 134217728 bytes (128 MiB)

    cvt_kernel<<<4096, 256, 0, stream>>>(x, xb);
    wtrans_kernel<<<dim3(32, 32, 4), 256, 0, stream>>>(Wq, Wk, Wv, Wo, WqkvT, WoT);
    gemm_qkv<<<dim3(384), 512, 0, stream>>>(xb, WqkvT, qkv);
    vtrans_kernel<<<dim3(32, 2, 32), 256, 0, stream>>>(qkv, vt);
    attn_kernel<<<dim3(16, 32), 128, 0, stream>>>(qkv, vt, ctx);
    gemm_bt<float><<<dim3(16, 32), 256, 0, stream>>>(ctx, WoT, out, B_ * S_, D_, D_);
}

// Round 3
// 417.052 us; speedup vs baseline: 1.0352x; 1.0352x over previous
//
#include <hip/hip_runtime.h>

typedef __bf16 bf16;
typedef __bf16 bf16x4 __attribute__((ext_vector_type(4)));
typedef __bf16 bf16x8 __attribute__((ext_vector_type(8)));
typedef float f32x4 __attribute__((ext_vector_type(4)));

#define B_ 2
#define S_ 2048
#define D_ 2048
#define H_ 16
#define DH_ 128
#define QKVN 6144

__device__ __forceinline__ void async_load16(const bf16* g, bf16* l) {
    __builtin_amdgcn_global_load_lds((const __attribute__((address_space(1))) void*)g,
                                     (__attribute__((address_space(3))) void*)l, 16, 0, 0);
}

__device__ __forceinline__ unsigned int bf16_bits(float x) {
    bf16 h = (bf16)x;
    return (unsigned int)__builtin_bit_cast(unsigned short, h);
}

// ---------------- x cast: f32 -> bf16, 8 elems/thread -----------------------------
__global__ __launch_bounds__(256) void cvt_kernel(const float* __restrict__ src,
                                                  bf16* __restrict__ dst) {
    size_t i = (size_t)blockIdx.x * 256 + threadIdx.x;
    const float4* s = (const float4*)src;
    float4 a = s[2 * i], b = s[2 * i + 1];
    bf16x8 o;
    o[0] = (bf16)a.x; o[1] = (bf16)a.y; o[2] = (bf16)a.z; o[3] = (bf16)a.w;
    o[4] = (bf16)b.x; o[5] = (bf16)b.y; o[6] = (bf16)b.z; o[7] = (bf16)b.w;
    *(bf16x8*)(dst + 8 * i) = o;
}

// ------- weight transpose + cast: W[K][N] f32 -> Wt[N][K] bf16, 4 matrices --------
__global__ __launch_bounds__(256) void wtrans_kernel(const float* __restrict__ Wq,
                                                     const float* __restrict__ Wk,
                                                     const float* __restrict__ Wv,
                                                     const float* __restrict__ Wo,
                                                     bf16* __restrict__ WqkvT,
                                                     bf16* __restrict__ WoT) {
    __shared__ unsigned int tile[64][65];  // bf16 bits in low half
    int z = blockIdx.z;
    const float* src = (z == 0) ? Wq : (z == 1) ? Wk : (z == 2) ? Wv : Wo;
    bf16* dst = (z < 3) ? (WqkvT + (size_t)z * D_ * D_) : WoT;
    int r0 = blockIdx.y * 64, c0 = blockIdx.x * 64;
    int t = threadIdx.x;
    int tr = t >> 4, tc4 = (t & 15) * 4;
#pragma unroll
    for (int it = 0; it < 4; ++it) {
        int r = it * 16 + tr;
        float4 v = *(const float4*)(src + (size_t)(r0 + r) * D_ + c0 + tc4);
        tile[r][tc4 + 0] = bf16_bits(v.x);
        tile[r][tc4 + 1] = bf16_bits(v.y);
        tile[r][tc4 + 2] = bf16_bits(v.z);
        tile[r][tc4 + 3] = bf16_bits(v.w);
    }
    __syncthreads();
#pragma unroll
    for (int it = 0; it < 4; ++it) {
        int a = it * 16 + tr;
        unsigned u0 = tile[tc4 + 0][a], u1 = tile[tc4 + 1][a];
        unsigned u2 = tile[tc4 + 2][a], u3 = tile[tc4 + 3][a];
        uint2 v;
        v.x = (u0 & 0xffffu) | (u1 << 16);
        v.y = (u2 & 0xffffu) | (u3 << 16);
        *(uint2*)(dst + (size_t)(c0 + a) * D_ + r0 + tc4) = v;
    }
}

// ---------------- V transpose: qkv[:,4096+h*128+dh] -> vt[bh][dh][s], bf16 --------
__global__ __launch_bounds__(256) void vtrans_kernel(const bf16* __restrict__ qkv,
                                                     bf16* __restrict__ vt) {
    __shared__ unsigned int tile[64][65];
    int bh = blockIdx.z;
    int b = bh >> 4, h = bh & 15;
    int s0 = blockIdx.x * 64, d0 = blockIdx.y * 64;
    int t = threadIdx.x, tr = t >> 4, tc4 = (t & 15) * 4;
#pragma unroll
    for (int it = 0; it < 4; ++it) {
        int r = it * 16 + tr;  // s offset
        uint2 v = *(const uint2*)(qkv + (size_t)(b * S_ + s0 + r) * QKVN + 2 * D_ + h * DH_ + d0 + tc4);
        tile[r][tc4 + 0] = v.x & 0xffffu;
        tile[r][tc4 + 1] = v.x >> 16;
        tile[r][tc4 + 2] = v.y & 0xffffu;
        tile[r][tc4 + 3] = v.y >> 16;
    }
    __syncthreads();
#pragma unroll
    for (int it = 0; it < 4; ++it) {
        int a = it * 16 + tr;  // dh offset
        unsigned u0 = tile[tc4 + 0][a], u1 = tile[tc4 + 1][a];
        unsigned u2 = tile[tc4 + 2][a], u3 = tile[tc4 + 3][a];
        uint2 v;
        v.x = (u0 & 0xffffu) | (u1 << 16);
        v.y = (u2 & 0xffffu) | (u3 << 16);
        *(uint2*)(vt + (size_t)bh * DH_ * S_ + (size_t)(d0 + a) * S_ + s0 + tc4) = v;
    }
}

// ---------------- m97-style GEMM: C[M][N] = A[M][K] @ Bt[N][K]^T ------------------
template <typename CT>
__global__ __launch_bounds__(256) void gemm_bt(const bf16* __restrict__ A,
                                               const bf16* __restrict__ Bt,
                                               CT* __restrict__ C,
                                               int M, int N, int K) {
    __shared__ __align__(16) bf16 As[128 * 32];
    __shared__ __align__(16) bf16 Bs[128 * 32];
    int t = threadIdx.x;
    int w = t >> 6, l = t & 63;
    int quad = l >> 4, lr = l & 15;
    int wr = w >> 1, wc = w & 1;
    size_t m0 = (size_t)blockIdx.y * 128, n0 = (size_t)blockIdx.x * 128;
    int srow = l >> 2, scol = (l & 3) * 8;

    f32x4 acc[4][4];
#pragma unroll
    for (int i = 0; i < 4; ++i)
#pragma unroll
        for (int j = 0; j < 4; ++j) acc[i][j] = (f32x4){0.f, 0.f, 0.f, 0.f};

    for (int k0 = 0; k0 < K; k0 += 32) {
        __syncthreads();
#pragma unroll
        for (int i = 0; i < 2; ++i) {
            int c = w * 2 + i;
            async_load16(A + (m0 + c * 16 + srow) * (size_t)K + k0 + scol, As + c * 512);
            async_load16(Bt + (n0 + c * 16 + srow) * (size_t)K + k0 + scol, Bs + c * 512);
        }
        asm volatile("s_waitcnt vmcnt(0)" ::: "memory");
        __syncthreads();
        bf16x8 af[4], bfr[4];
#pragma unroll
        for (int i = 0; i < 4; ++i) af[i] = *(const bf16x8*)(As + (wr * 64 + i * 16 + lr) * 32 + quad * 8);
#pragma unroll
        for (int j = 0; j < 4; ++j) bfr[j] = *(const bf16x8*)(Bs + (wc * 64 + j * 16 + lr) * 32 + quad * 8);
#pragma unroll
        for (int i = 0; i < 4; ++i)
#pragma unroll
            for (int j = 0; j < 4; ++j)
                acc[i][j] = __builtin_amdgcn_mfma_f32_16x16x32_bf16(af[i], bfr[j], acc[i][j], 0, 0, 0);
    }

    size_t bm = m0 + wr * 64 + quad * 4;
    size_t bn = n0 + wc * 64 + lr;
#pragma unroll
    for (int i = 0; i < 4; ++i)
#pragma unroll
        for (int j = 0; j < 4; ++j)
#pragma unroll
            for (int r = 0; r < 4; ++r)
                C[(bm + i * 16 + r) * (size_t)N + bn + j * 16] = (CT)acc[i][j][r];
}

// ========== 256x256 8-phase GEMM for QKV: C[4096][6144] = A[4096][2048] @ Bt^T ====
// Swizzle (round 3 fix): Guideline-4 chunk-XOR for 128B-row tiles —
// physical 16B-chunk (row, c) holds logical (row, c ^ (row&7)).  A 64-lane
// ds_read_b128 at fixed col-slot covers all 8 slots x 8 lanes = all 32 banks
// evenly (verified formula: attn K-tile, +89%).  Staging: global SOURCE is
// inverse-permuted per row (global_load_lds dest stays linear); each 8-lane
// row-group still reads one full 128B segment -> coalesced.
// T3/T4: 4 phases per K-tile, half-tile staging in consumption order
// A0,B0,B1,A1; counted vmcnt BEFORE a barrier (collective guarantee).
// T5: setprio around each 16-MFMA cluster.
#define QK_K 2048
#define QK_N 6144

__device__ __forceinline__ bf16x8 lds_frag(const bf16* tile, int row, int colByte) {
    int off = row * 128 + (colByte ^ ((row & 7) << 4));
    return *(const bf16x8*)((const char*)tile + off);
}

template <int MH, int NH>
__device__ __forceinline__ void mmaq8(f32x4 (&acc)[8][4], const bf16x8 (&afr)[4][2],
                                      const bf16x8 (&bf)[2][2]) {
    __builtin_amdgcn_s_setprio(1);
#pragma unroll
    for (int i = 0; i < 4; ++i)
#pragma unroll
        for (int j = 0; j < 2; ++j)
#pragma unroll
            for (int kk = 0; kk < 2; ++kk)
                acc[MH * 4 + i][NH * 2 + j] = __builtin_amdgcn_mfma_f32_16x16x32_bf16(
                    afr[i][kk], bf[j][kk], acc[MH * 4 + i][NH * 2 + j], 0, 0, 0);
    __builtin_amdgcn_s_setprio(0);
}

__global__ __launch_bounds__(512, 2) void gemm_qkv(const bf16* __restrict__ A,
                                                   const bf16* __restrict__ Bt,
                                                   bf16* __restrict__ C) {
    __shared__ __align__(16) bf16 As[2][256 * 64];
    __shared__ __align__(16) bf16 Bs[2][256 * 64];

    int t = threadIdx.x;
    int wid = t >> 6, lane = t & 63;
    int quad = lane >> 4, lr = lane & 15;
    int wr = wid >> 2, wn = wid & 3;  // 2 x 4 wave grid

    // XCD swizzle: 384 wgs, 8 XCDs x 48. Column-major: each XCD owns 3 disjoint
    // B-panels (read exactly once chip-wide); A panels stream (L3-resident).
    int bid = blockIdx.x;
    int swz = (bid & 7) * 48 + (bid >> 3);
    int tn = swz >> 4, tm = swz & 15;
    size_t m0 = (size_t)tm * 256, n0 = (size_t)tn * 256;

    // staging geometry: chunk idx = r*512 + t; row = idx>>3, col-chunk = idx&7;
    // source col-chunk permuted by row&7 (inverse of the read-side XOR).
    int row_r[2], c8s_r[2];
#pragma unroll
    for (int r = 0; r < 2; ++r) {
        int idx = r * 512 + t;
        row_r[r] = idx >> 3;
        c8s_r[r] = (idx & 7) ^ (row_r[r] & 7);
    }

    auto stA = [&](int kt, int bufi, int h) {
#pragma unroll
        for (int r = 0; r < 2; ++r)
            async_load16(A + (m0 + h * 128 + row_r[r]) * (size_t)QK_K + kt * 64 + c8s_r[r] * 8,
                         &As[bufi][(h * 1024 + r * 512 + wid * 64) * 8]);
    };
    auto stB = [&](int kt, int bufi, int h) {
#pragma unroll
        for (int r = 0; r < 2; ++r)
            async_load16(Bt + (n0 + h * 128 + row_r[r]) * (size_t)QK_K + kt * 64 + c8s_r[r] * 8,
                         &Bs[bufi][(h * 1024 + r * 512 + wid * 64) * 8]);
    };

    f32x4 acc[8][4];
#pragma unroll
    for (int i = 0; i < 8; ++i)
#pragma unroll
        for (int j = 0; j < 4; ++j) acc[i][j] = (f32x4){0.f, 0.f, 0.f, 0.f};

    bf16x8 afr[4][2], bf0[2][2], bf1[2][2];

    auto readA = [&](int bufi, int mh) {
#pragma unroll
        for (int i = 0; i < 4; ++i)
#pragma unroll
            for (int kk = 0; kk < 2; ++kk)
                afr[i][kk] = lds_frag(As[bufi], mh * 128 + wr * 64 + i * 16 + lr, kk * 64 + quad * 16);
    };
    auto readB = [&](int bufi, int nh, bf16x8 (&bf)[2][2]) {
#pragma unroll
        for (int j = 0; j < 2; ++j)
#pragma unroll
            for (int kk = 0; kk < 2; ++kk)
                bf[j][kk] = lds_frag(Bs[bufi], nh * 128 + wn * 32 + j * 16 + lr, kk * 64 + quad * 16);
    };

    // prologue: stage tile 0 in consumption-guard order A0,B0,B1,A1 (8 loads)
    stA(0, 0, 0);
    stB(0, 0, 0);
    stB(0, 0, 1);
    stA(0, 0, 1);
    asm volatile("s_waitcnt vmcnt(4)" ::: "memory");  // A0,B0 done
    __builtin_amdgcn_s_barrier();

    const int NKT = QK_K / 64;  // 32
    for (int kt = 0; kt < NKT - 1; ++kt) {
        int cb = kt & 1, nb = cb ^ 1;
        // ---- phase 0: quadrant (0,0); stage A0' ----
        readA(cb, 0);
        readB(cb, 0, bf0);
        stA(kt + 1, nb, 0);
        asm volatile("s_waitcnt vmcnt(4)" ::: "memory");  // guard ph1's B1
        __builtin_amdgcn_s_barrier();
        asm volatile("s_waitcnt lgkmcnt(0)" ::: "memory");
        __builtin_amdgcn_sched_barrier(0);
        mmaq8<0, 0>(acc, afr, bf0);
        __builtin_amdgcn_s_barrier();
        // ---- phase 1: quadrant (0,1); stage B0' ----
        readB(cb, 1, bf1);
        stB(kt + 1, nb, 0);
        asm volatile("s_waitcnt vmcnt(4)" ::: "memory");  // guard ph2's A1
        __builtin_amdgcn_s_barrier();
        asm volatile("s_waitcnt lgkmcnt(0)" ::: "memory");
        __builtin_amdgcn_sched_barrier(0);
        mmaq8<0, 1>(acc, afr, bf1);
        __builtin_amdgcn_s_barrier();
        // ---- phase 2: quadrant (1,0); stage B1' ----
        readA(cb, 1);
        stB(kt + 1, nb, 1);
        __builtin_amdgcn_s_barrier();  // ph3 reads nothing: no vmcnt here
        asm volatile("s_waitcnt lgkmcnt(0)" ::: "memory");
        __builtin_amdgcn_sched_barrier(0);
        mmaq8<1, 0>(acc, afr, bf0);
        __builtin_amdgcn_s_barrier();
        // ---- phase 3: quadrant (1,1); stage A1' ----
        stA(kt + 1, nb, 1);
        asm volatile("s_waitcnt vmcnt(4)" ::: "memory");  // guard next ph0's A0',B0'
        __builtin_amdgcn_s_barrier();
        mmaq8<1, 1>(acc, afr, bf1);
        __builtin_amdgcn_s_barrier();
    }

    {  // peeled last tile (no staging)
        int cb = (NKT - 1) & 1;
        readA(cb, 0);
        readB(cb, 0, bf0);
        asm volatile("s_waitcnt vmcnt(2)" ::: "memory");  // guard B1
        __builtin_amdgcn_s_barrier();
        asm volatile("s_waitcnt lgkmcnt(0)" ::: "memory");
        __builtin_amdgcn_sched_barrier(0);
        mmaq8<0, 0>(acc, afr, bf0);
        __builtin_amdgcn_s_barrier();
        readB(cb, 1, bf1);
        asm volatile("s_waitcnt vmcnt(0)" ::: "memory");  // guard A1
        __builtin_amdgcn_s_barrier();
        asm volatile("s_waitcnt lgkmcnt(0)" ::: "memory");
        __builtin_amdgcn_sched_barrier(0);
        mmaq8<0, 1>(acc, afr, bf1);
        __builtin_amdgcn_s_barrier();
        readA(cb, 1);
        __builtin_amdgcn_s_barrier();
        asm volatile("s_waitcnt lgkmcnt(0)" ::: "memory");
        __builtin_amdgcn_sched_barrier(0);
        mmaq8<1, 0>(acc, afr, bf0);
        __builtin_amdgcn_s_barrier();
        mmaq8<1, 1>(acc, afr, bf1);
    }

    // epilogue: C/D layout col=lr, row=quad*4+r per 16x16 frag
#pragma unroll
    for (int mh = 0; mh < 2; ++mh)
#pragma unroll
        for (int i = 0; i < 4; ++i)
#pragma unroll
            for (int nh = 0; nh < 2; ++nh)
#pragma unroll
                for (int j = 0; j < 2; ++j)
#pragma unroll
                    for (int r = 0; r < 4; ++r) {
                        size_t row = m0 + mh * 128 + wr * 64 + i * 16 + quad * 4 + r;
                        size_t col = n0 + nh * 128 + wn * 32 + j * 16 + lr;
                        C[row * QK_N + col] = (bf16)acc[mh * 4 + i][nh * 2 + j][r];
                    }
}

// ---------------- flash attention, causal ----------------------------------------
__global__ __launch_bounds__(128) void attn_kernel(const bf16* __restrict__ qkv,
                                                   const bf16* __restrict__ vt,
                                                   bf16* __restrict__ ctx) {
    __shared__ __align__(16) bf16 Ks[2][64 * 128];    // [key][16B-chunk c ^ (key&7)]
    __shared__ __align__(16) bf16 Vts[2][128 * 64];   // [dh][16B-chunk c ^ (dh&7)]
    __shared__ __align__(16) bf16 Ps[2][32][68];      // per-wave P round-trip

    int y = blockIdx.y;
    int p = blockIdx.x;
    int b = y >> 4, h = y & 15;
    int t = threadIdx.x, w = t >> 6, l = t & 63;
    int quad = l >> 4, lr = l & 15;

    const bf16* qbase = qkv + (size_t)b * S_ * QKVN + h * DH_;
    const bf16* kbase = qbase + D_;
    const bf16* vbase = vt + (size_t)y * DH_ * S_;

    const int qtA = p, qtB = 31 - p;
    const int nA = p + 1;  // iters for tile A; total 33

    auto stage = [&](int kt, int bi) {
#pragma unroll
        for (int ii = 0; ii < 8; ++ii) {
            int i = 8 * w + ii;
            int row = 4 * i + (l >> 4);
            int cl = (l & 15) ^ (row & 7);
            async_load16(kbase + (size_t)(kt * 64 + row) * QKVN + cl * 8, Ks[bi] + i * 512);
        }
#pragma unroll
        for (int ii = 0; ii < 8; ++ii) {
            int i = 8 * w + ii;
            int dh = 8 * i + (l >> 3);
            int cl = (l & 7) ^ (dh & 7);
            async_load16(vbase + (size_t)dh * S_ + kt * 64 + cl * 8, Vts[bi] + i * 512);
        }
    };

    const float sc2 = 0.12751745f;  // (1/sqrt(128)) * log2(e), folded into Q

    int qt = qtA, q0 = qt * 64;
    bf16x8 qf[2][4];
    auto loadQ = [&]() {
#pragma unroll
        for (int g = 0; g < 2; ++g)
#pragma unroll
            for (int kk = 0; kk < 4; ++kk) {
                bf16x8 raw = *(const bf16x8*)(qbase + (size_t)(q0 + w * 32 + g * 16 + lr) * QKVN + kk * 32 + quad * 8);
#pragma unroll
                for (int e = 0; e < 8; ++e) qf[g][kk][e] = (bf16)((float)raw[e] * sc2);
            }
    };
    loadQ();

    float L_r[2][4];
    f32x4 o[2][8];
#pragma unroll
    for (int g = 0; g < 2; ++g) {
#pragma unroll
        for (int r = 0; r < 4; ++r) L_r[g][r] = 0.f;
#pragma unroll
        for (int nt = 0; nt < 8; ++nt) o[g][nt] = (f32x4){0.f, 0.f, 0.f, 0.f};
    }

    auto epilogue = [&](int q0e) {
#pragma unroll
        for (int g = 0; g < 2; ++g) {
#pragma unroll
            for (int d = 1; d < 16; d <<= 1)
#pragma unroll
                for (int r = 0; r < 4; ++r) L_r[g][r] += __shfl_xor(L_r[g][r], d, 64);
#pragma unroll
            for (int r = 0; r < 4; ++r) {
                float inv = __builtin_amdgcn_rcpf(L_r[g][r]);
                int q = q0e + w * 32 + g * 16 + quad * 4 + r;
#pragma unroll
                for (int nt = 0; nt < 8; ++nt)
                    ctx[(size_t)(b * S_ + q) * D_ + h * DH_ + nt * 16 + lr] = (bf16)(o[g][nt][r] * inv);
            }
        }
    };

    stage(0, 0);  // prologue

    for (int it = 0; it < 33; ++it) {
        int buf = it & 1;
        asm volatile("s_waitcnt vmcnt(0)" ::: "memory");
        __syncthreads();
        if (it + 1 < 33) {
            int nit = it + 1;
            int nkt = (nit < nA) ? nit : (nit - nA);
            stage(nkt, buf ^ 1);  // in flight across this iter's compute
        }
        int kt = (it < nA) ? it : (it - nA);

        // S = Q K^T: 2 row-groups x 64 keys; each kf feeds 2 MFMAs
        f32x4 s[2][4];
#pragma unroll
        for (int g = 0; g < 2; ++g)
#pragma unroll
            for (int jt = 0; jt < 4; ++jt) s[g][jt] = (f32x4){0.f, 0.f, 0.f, 0.f};
#pragma unroll
        for (int kk = 0; kk < 4; ++kk)
#pragma unroll
            for (int jt = 0; jt < 4; ++jt) {
                bf16x8 kf = *(const bf16x8*)(Ks[buf] + (jt * 16 + lr) * 128 + ((4 * kk + quad) ^ (lr & 7)) * 8);
                s[0][jt] = __builtin_amdgcn_mfma_f32_16x16x32_bf16(qf[0][kk], kf, s[0][jt], 0, 0, 0);
                s[1][jt] = __builtin_amdgcn_mfma_f32_16x16x32_bf16(qf[1][kk], kf, s[1][jt], 0, 0, 0);
            }

        // exp2 (m=0) + mask (diag k-tile only) + per-lane L accumulation + P store
        bool diag = (kt == qt);
#pragma unroll
        for (int g = 0; g < 2; ++g) {
#pragma unroll
            for (int jt = 0; jt < 4; ++jt) {
                int keyi = jt * 16 + lr;
#pragma unroll
                for (int r = 0; r < 4; ++r) {
                    float s2 = s[g][jt][r];
                    if (diag && keyi > w * 32 + g * 16 + quad * 4 + r) s2 = -3.0e38f;
                    float pv = __builtin_amdgcn_exp2f(s2);
                    s[g][jt][r] = pv;
                    L_r[g][r] += pv;
                }
            }
#pragma unroll
            for (int jt = 0; jt < 4; ++jt)
#pragma unroll
                for (int r = 0; r < 4; ++r)
                    Ps[w][g * 16 + quad * 4 + r][jt * 16 + lr] = (bf16)s[g][jt][r];
        }
        asm volatile("s_waitcnt lgkmcnt(0)" ::: "memory");  // per-wave Ps region

        // O += P @ V: each vf feeds 2 MFMAs
#pragma unroll
        for (int ks = 0; ks < 2; ++ks) {
            bf16x8 pf[2];
#pragma unroll
            for (int g = 0; g < 2; ++g) {
                const bf16* pp = &Ps[w][g * 16 + lr][ks * 32 + quad * 8];
                bf16x4 lo = *(const bf16x4*)pp;
                bf16x4 hi = *(const bf16x4*)(pp + 4);
                pf[g] = __builtin_shufflevector(lo, hi, 0, 1, 2, 3, 4, 5, 6, 7);
            }
#pragma unroll
            for (int nt = 0; nt < 8; ++nt) {
                bf16x8 vf = *(const bf16x8*)(Vts[buf] + (nt * 16 + lr) * 64 + ((4 * ks + quad) ^ (lr & 7)) * 8);
                o[0][nt] = __builtin_amdgcn_mfma_f32_16x16x32_bf16(pf[0], vf, o[0][nt], 0, 0, 0);
                o[1][nt] = __builtin_amdgcn_mfma_f32_16x16x32_bf16(pf[1], vf, o[1][nt], 0, 0, 0);
            }
        }

        // tile switch A -> B after A's diagonal iteration
        if (it == nA - 1) {
            epilogue(q0);
            qt = qtB;
            q0 = qt * 64;
            loadQ();
#pragma unroll
            for (int g = 0; g < 2; ++g) {
#pragma unroll
                for (int r = 0; r < 4; ++r) L_r[g][r] = 0.f;
#pragma unroll
                for (int nt = 0; nt < 8; ++nt) o[g][nt] = (f32x4){0.f, 0.f, 0.f, 0.f};
            }
        }
    }

    epilogue(q0);  // tile B
}

extern "C" void kernel_launch(void* const* d_in, const int* in_sizes, int n_in,
                              void* d_out, int out_size, void* d_ws, size_t ws_size,
                              hipStream_t stream) {
    const float* x  = (const float*)d_in[0];
    const float* Wq = (const float*)d_in[1];
    const float* Wk = (const float*)d_in[2];
    const float* Wv = (const float*)d_in[3];
    const float* Wo = (const float*)d_in[4];
    float* out = (float*)d_out;

    char* ws = (char*)d_ws;
    bf16* WqkvT = (bf16*)(ws);                       // 3*2048*2048*2 = 25165824
    bf16* WoT   = (bf16*)(ws + 25165824);            // 2048*2048*2   =  8388608
    bf16* qkv   = (bf16*)(ws + 33554432);            // 4096*6144*2   = 50331648
    bf16* vt    = (bf16*)(ws + 83886080);            // 32*128*2048*2 = 16777216
    bf16* ctx   = (bf16*)(ws + 100663296);           // 4096*2048*2   = 16777216
    bf16* xb    = (bf16*)(ws + 117440512);           // 4096*2048*2   = 16777216
    // total ws use: 134217728 bytes (128 MiB)

    cvt_kernel<<<4096, 256, 0, stream>>>(x, xb);
    wtrans_kernel<<<dim3(32, 32, 4), 256, 0, stream>>>(Wq, Wk, Wv, Wo, WqkvT, WoT);
    gemm_qkv<<<dim3(384), 512, 0, stream>>>(xb, WqkvT, qkv);
    vtrans_kernel<<<dim3(32, 2, 32), 256, 0, stream>>>(qkv, vt);
    attn_kernel<<<dim3(16, 32), 128, 0, stream>>>(qkv, vt, ctx);
    gemm_bt<float><<<dim3(16, 32), 256, 0, stream>>>(ctx, WoT, out, B_ * S_, D_, D_);
}